// Round 16
// baseline (406.734 us; speedup 1.0000x reference)
//
#include <hip/hip_runtime.h>
#include <hip/hip_fp16.h>

typedef _Float16 f16;
typedef _Float16 f16x8 __attribute__((ext_vector_type(8)));
typedef float f32x4 __attribute__((ext_vector_type(4)));

#define MFMA(a,b,c) __builtin_amdgcn_mfma_f32_16x16x32_f16((a),(b),(c),0,0,0)

// raw barrier: drain LDS only; leave global loads in flight (no vmcnt(0))
#define BAR() do { \
  asm volatile("s_waitcnt lgkmcnt(0)" ::: "memory"); \
  __builtin_amdgcn_sched_barrier(0); \
  __builtin_amdgcn_s_barrier(); \
  __builtin_amdgcn_sched_barrier(0); \
} while (0)

// B=16384, IN=512, HID=1024, OUT=512, E=16, K=4
// ws: w1fr 16MB + w2fr 16MB + routing ~2.6MB = ~34.6MB (known-safe)

// w1: [16][512][1024] -> fragment fid=((e*64+n0)*16+kc), lane l, elem i
//   = w1[e][kc*32+(l>>4)*8+i][n0*16+(l&15)]
__global__ void k_cvt_w1(const float* __restrict__ w1, f16* __restrict__ w1fr) {
  int fid = blockIdx.x * 4 + (threadIdx.x >> 6);
  int l = threadIdx.x & 63;
  int e = fid >> 10, n0 = (fid >> 4) & 63, kc = fid & 15;
  int kbase = kc * 32 + (l >> 4) * 8;
  int col = n0 * 16 + (l & 15);
  const float* src = w1 + ((size_t)e * 512 + kbase) * 1024 + col;
  f16x8 o;
  #pragma unroll
  for (int i = 0; i < 8; i++) o[i] = (f16)src[(size_t)i * 1024];
  *(f16x8*)(w1fr + (size_t)fid * 512 + l * 8) = o;
}

// w2: [16][1024][512] -> frag fid=((e*32+n0)*32+kc)
__global__ void k_cvt_w2(const float* __restrict__ w2, f16* __restrict__ w2fr) {
  int fid = blockIdx.x * 4 + (threadIdx.x >> 6);
  int l = threadIdx.x & 63;
  int e = fid >> 10, n0 = (fid >> 5) & 31, kc = fid & 31;
  int kbase = kc * 32 + (l >> 4) * 8;
  int col = n0 * 16 + (l & 15);
  const float* src = w2 + ((size_t)e * 1024 + kbase) * 512 + col;
  f16x8 o;
  #pragma unroll
  for (int i = 0; i < 8; i++) o[i] = (f16)src[(size_t)i * 512];
  *(f16x8*)(w2fr + (size_t)fid * 512 + l * 8) = o;
}

// ---------------- gating ----------------
__global__ void k_gate(const float* __restrict__ x, const float* __restrict__ wg,
                       int* __restrict__ tk_idx, float* __restrict__ tk_gate) {
  int w = threadIdx.x >> 6, l = threadIdx.x & 63;
  int r = blockIdx.x * 4 + w;
  float p[16];
  #pragma unroll
  for (int e = 0; e < 16; e++) p[e] = 0.f;
  const float* xr = x + (size_t)r * 512;
  #pragma unroll
  for (int t = 0; t < 8; t++) {
    float xv = xr[t * 64 + l];
    const float* wrow = wg + (t * 64 + l) * 16;
    #pragma unroll
    for (int e = 0; e < 16; e++) p[e] += xv * wrow[e];
  }
  #pragma unroll
  for (int e = 0; e < 16; e++) {
    float v = p[e];
    #pragma unroll
    for (int m = 32; m >= 1; m >>= 1) v += __shfl_xor(v, m);
    p[e] = v;
  }
  unsigned chosen = 0;
  float bv[4]; int bi[4];
  #pragma unroll
  for (int j = 0; j < 4; j++) {
    float best = -3.4e38f; int be = 0;
    #pragma unroll
    for (int e = 0; e < 16; e++) {
      bool ok = !((chosen >> e) & 1u) && (p[e] > best);
      if (ok) { best = p[e]; be = e; }
    }
    chosen |= 1u << be; bv[j] = best; bi[j] = be;
  }
  float m0 = bv[0];
  float e0 = __expf(bv[0] - m0), e1 = __expf(bv[1] - m0),
        e2 = __expf(bv[2] - m0), e3 = __expf(bv[3] - m0);
  float s = e0 + e1 + e2 + e3;
  if (l == 0) {
    *(int4*)(tk_idx + (size_t)r * 4) = make_int4(bi[0], bi[1], bi[2], bi[3]);
    *(float4*)(tk_gate + (size_t)r * 4) = make_float4(e0 / s, e1 / s, e2 / s, e3 / s);
  }
}

// ---------------- routing (deterministic compaction) ----------------
__global__ void k_route_count(const int* __restrict__ tk_idx, int* __restrict__ partial) {
  int e = blockIdx.x >> 6, chunk = blockIdx.x & 63;
  int t = threadIdx.x;
  int row = chunk * 256 + t;
  int4 tk = ((const int4*)tk_idx)[row];
  bool match = (tk.x == e) || (tk.y == e) || (tk.z == e) || (tk.w == e);
  unsigned long long m = __ballot(match);
  __shared__ int wc[4];
  if ((t & 63) == 0) wc[t >> 6] = (int)__popcll(m);
  __syncthreads();
  if (t == 0) partial[e * 64 + chunk] = wc[0] + wc[1] + wc[2] + wc[3];
}

__global__ void k_route_scan(const int* __restrict__ partial, int* __restrict__ chunk_base,
                             int* __restrict__ count) {
  int l = threadIdx.x; // 64 threads
  for (int e = 0; e < 16; e++) {
    int v = partial[e * 64 + l];
    int orig = v;
    #pragma unroll
    for (int off = 1; off < 64; off <<= 1) {
      int u = __shfl_up(v, off);
      if (l >= off) v += u;
    }
    chunk_base[e * 64 + l] = v - orig;
    if (l == 63) count[e] = v;
  }
}

__global__ void k_route_scatter(const int* __restrict__ tk_idx, const float* __restrict__ tk_gate,
                                const int* __restrict__ chunk_base, int* __restrict__ rows_pk,
                                float* __restrict__ gates_l) {
  int e = blockIdx.x >> 6, chunk = blockIdx.x & 63;
  int t = threadIdx.x, w = t >> 6, l = t & 63;
  int row = chunk * 256 + t;
  int4 tk = ((const int4*)tk_idx)[row];
  int j = (tk.x == e) ? 0 : (tk.y == e) ? 1 : (tk.z == e) ? 2 : (tk.w == e) ? 3 : -1;
  bool match = (j >= 0);
  unsigned long long m = __ballot(match);
  __shared__ int wc[4];
  if (l == 0) wc[w] = (int)__popcll(m);
  __syncthreads();
  int wbase = 0;
  #pragma unroll
  for (int i = 0; i < 4; i++) if (i < w) wbase += wc[i];
  if (match) {
    int pos = (int)__popcll(m & ((1ULL << l) - 1ULL));
    int idx = e * 16384 + chunk_base[e * 64 + chunk] + wbase + pos;
    rows_pk[idx] = row | (j << 16);
    gates_l[idx] = tk_gate[(size_t)row * 4 + j];
  }
}

// ---------------- zero output ----------------
__global__ void k_zero(float4* __restrict__ y4) {
  y4[blockIdx.x * 256 + threadIdx.x] = make_float4(0.f, 0.f, 0.f, 0.f);
}

// ---------------- fused expert FFN: BM=64, 8 waves, x-resident, rotate prefetch ----------------
// R15's layout (x staged once read-only, hc=512, seg-XOR 0-conflict, 7 BARs) +
// R6's register discipline (explicit rotate-by-1 weight prefetch, unroll 1) so the
// 256-reg/wave budget at 2 waves/SIMD is respected -> no spill (R15's 62MB WRITE excess).
__global__ __launch_bounds__(512, 2) void k_expert(
    const float* __restrict__ x, const f16* __restrict__ w1fr, const f16* __restrict__ w2fr,
    const float* __restrict__ b1, const float* __restrict__ b2,
    const int* __restrict__ count, const int* __restrict__ rows_pk,
    const float* __restrict__ gates_l, float* __restrict__ y)
{
  int p = blockIdx.x;
  int xcd = p & 7, s = p >> 3;
  int e = (xcd << 1) | (s >> 8);
  int rb = s & 255;
  int cnt = count[e];
  int mstart = rb * 64;
  if (mstart >= cnt) return;
  int nvalid = cnt - mstart; if (nvalid > 64) nvalid = 64;

  __shared__ f16 x_lds[64 * 512];   // 64KB, staged once, seg-XOR swizzled
  __shared__ f16 h_lds[64 * 512];   // 64KB (512-col hc chunk), seg-XOR swizzled
  __shared__ int rowarr[64];
  __shared__ float gatearr[64];
  __shared__ float red[2][8][64];   // 4KB

  int t = threadIdx.x, w = t >> 6, l = t & 63;
  int lq = l >> 4, lr = l & 15;

  if (t < 64) {
    int idx = (t < nvalid) ? t : (nvalid - 1);
    int src = e * 16384 + mstart + idx;
    rowarr[t] = rows_pk[src];
    gatearr[t] = gates_l[src];
  }
  BAR();

  char* xb = (char*)x_lds;
  char* hb = (char*)h_lds;

  // ---- stage x once: 8 threads/row, 8 segs (16B f16 = 32B f32 src) each ----
  {
    int srow = t >> 3, sj = t & 7;
    const float* sp = x + (size_t)(rowarr[srow] & 0xFFFF) * 512;
    #pragma unroll
    for (int j = 0; j < 8; j++) {
      int seg = sj + j * 8;                       // 0..63
      const float* qp = sp + seg * 8;
      float4 u0 = ((const float4*)qp)[0], u1 = ((const float4*)qp)[1];
      f16x8 v;
      v[0]=(f16)u0.x; v[1]=(f16)u0.y; v[2]=(f16)u0.z; v[3]=(f16)u0.w;
      v[4]=(f16)u1.x; v[5]=(f16)u1.y; v[6]=(f16)u1.z; v[7]=(f16)u1.w;
      int byte = srow * 1024 + ((seg ^ srow) & 63) * 16;
      *(f16x8*)(xb + byte) = v;
    }
  }
  BAR();   // x ready (and stays read-only for the whole kernel)

  const f16x8* w1f8 = (const f16x8*)w1fr;
  const f16x8* w2f8 = (const f16x8*)w2fr;

  f32x4 acc2[4][4];   // rows mf*16+lq*4+q, cols w*64+nf*16+lr
  #pragma unroll
  for (int a = 0; a < 4; a++)
    #pragma unroll
    for (int b = 0; b < 4; b++)
      #pragma unroll
      for (int q = 0; q < 4; q++) acc2[a][b][q] = 0.f;

  #pragma unroll 1
  for (int hc = 0; hc < 2; hc++) {
    // ---- stage 1: h[:, hc*512 + w*64+nf*16 ..] = x @ w1, K=512 — barrier-free,
    //      rotate-by-1 weight prefetch (bounded lookahead, no spill) ----
    f32x4 acc1[4][4];
    #pragma unroll
    for (int a = 0; a < 4; a++)
      #pragma unroll
      for (int b = 0; b < 4; b++)
        #pragma unroll
        for (int q = 0; q < 4; q++) acc1[a][b][q] = 0.f;

    const f16x8* bp1 = w1f8 + ((size_t)((e * 64 + hc * 32 + w * 4) * 16)) * 64 + l;
    f16x8 ba0 = bp1[0], ba1 = bp1[16 * 64], ba2 = bp1[32 * 64], ba3 = bp1[48 * 64];
    #pragma unroll 1
    for (int kcg = 0; kcg < 16; kcg++) {
      f16x8 bb0, bb1, bb2, bb3;
      if (kcg < 15) {
        bb0 = bp1[(kcg + 1) * 64];
        bb1 = bp1[16 * 64 + (kcg + 1) * 64];
        bb2 = bp1[32 * 64 + (kcg + 1) * 64];
        bb3 = bp1[48 * 64 + (kcg + 1) * 64];
      }
      int seg = kcg * 4 + lq;
      f16x8 av[4];
      #pragma unroll
      for (int mf = 0; mf < 4; mf++) {
        int row = mf * 16 + lr;
        av[mf] = *(const f16x8*)(xb + row * 1024 + ((seg ^ row) & 63) * 16);
      }
      #pragma unroll
      for (int mf = 0; mf < 4; mf++) {
        acc1[mf][0] = MFMA(av[mf], ba0, acc1[mf][0]);
        acc1[mf][1] = MFMA(av[mf], ba1, acc1[mf][1]);
        acc1[mf][2] = MFMA(av[mf], ba2, acc1[mf][2]);
        acc1[mf][3] = MFMA(av[mf], ba3, acc1[mf][3]);
      }
      if (kcg < 15) { ba0 = bb0; ba1 = bb1; ba2 = bb2; ba3 = bb3; }
    }

    BAR();   // prev hc's stage-2 h reads complete before overwrite
    // ---- h epilogue: bias + relu -> h_lds (chunk cols cc = w*64+nf*16+lr) ----
    #pragma unroll
    for (int nf = 0; nf < 4; nf++) {
      int cc = w * 64 + nf * 16 + lr;
      float bv = b1[e * 1024 + hc * 512 + cc];
      int segw = cc >> 3;
      int inb = (cc & 7) * 2;
      #pragma unroll
      for (int mf = 0; mf < 4; mf++)
        #pragma unroll
        for (int q = 0; q < 4; q++) {
          int row = mf * 16 + lq * 4 + q;
          float hv = fmaxf(acc1[mf][nf][q] + bv, 0.f);
          int byte = row * 1024 + ((segw ^ row) & 63) * 16 + inb;
          *(f16*)(hb + byte) = (f16)hv;
        }
    }
    BAR();   // h ready

    // ---- stage 2: acc2 += h_chunk @ w2, K=512 — barrier-free, rotate-by-1 ----
    const f16x8* bp2 = w2f8 + ((size_t)((e * 32 + w * 4) * 32 + hc * 16)) * 64 + l;
    f16x8 wa0 = bp2[0], wa1 = bp2[32 * 64], wa2 = bp2[64 * 64], wa3 = bp2[96 * 64];
    #pragma unroll 1
    for (int kc2 = 0; kc2 < 16; kc2++) {
      f16x8 wb0, wb1, wb2, wb3;
      if (kc2 < 15) {
        wb0 = bp2[(kc2 + 1) * 64];
        wb1 = bp2[32 * 64 + (kc2 + 1) * 64];
        wb2 = bp2[64 * 64 + (kc2 + 1) * 64];
        wb3 = bp2[96 * 64 + (kc2 + 1) * 64];
      }
      int seg = kc2 * 4 + lq;
      f16x8 av[4];
      #pragma unroll
      for (int mf = 0; mf < 4; mf++) {
        int row = mf * 16 + lr;
        av[mf] = *(const f16x8*)(hb + row * 1024 + ((seg ^ row) & 63) * 16);
      }
      #pragma unroll
      for (int mf = 0; mf < 4; mf++) {
        acc2[mf][0] = MFMA(av[mf], wa0, acc2[mf][0]);
        acc2[mf][1] = MFMA(av[mf], wa1, acc2[mf][1]);
        acc2[mf][2] = MFMA(av[mf], wa2, acc2[mf][2]);
        acc2[mf][3] = MFMA(av[mf], wa3, acc2[mf][3]);
      }
      if (kc2 < 15) { wa0 = wb0; wa1 = wb1; wa2 = wb2; wa3 = wb3; }
    }
  }

  // bias2: cols w*64 + nf*16 + lr
  #pragma unroll
  for (int nf = 0; nf < 4; nf++) {
    float bv = b2[e * 512 + w * 64 + nf * 16 + lr];
    #pragma unroll
    for (int mf = 0; mf < 4; mf++)
      #pragma unroll
      for (int q = 0; q < 4; q++) acc2[mf][nf][q] += bv;
  }

  // ---- softmax across full row (512 cols over 8 waves) ----
  float rmax[4][4];
  #pragma unroll
  for (int mf = 0; mf < 4; mf++)
    #pragma unroll
    for (int q = 0; q < 4; q++) {
      float v = acc2[mf][0][q];
      #pragma unroll
      for (int nf = 1; nf < 4; nf++) v = fmaxf(v, acc2[mf][nf][q]);
      #pragma unroll
      for (int m = 1; m < 16; m <<= 1) v = fmaxf(v, __shfl_xor(v, m));
      rmax[mf][q] = v;
    }
  if (lr == 0) {
    #pragma unroll
    for (int mf = 0; mf < 4; mf++)
      #pragma unroll
      for (int q = 0; q < 4; q++) red[0][w][mf * 16 + lq * 4 + q] = rmax[mf][q];
  }
  BAR();
  float gmax[4][4];
  #pragma unroll
  for (int mf = 0; mf < 4; mf++)
    #pragma unroll
    for (int q = 0; q < 4; q++) {
      int row = mf * 16 + lq * 4 + q;
      float v = red[0][0][row];
      #pragma unroll
      for (int ww = 1; ww < 8; ww++) v = fmaxf(v, red[0][ww][row]);
      gmax[mf][q] = v;
    }
  float psum[4][4];
  #pragma unroll
  for (int mf = 0; mf < 4; mf++)
    #pragma unroll
    for (int q = 0; q < 4; q++) psum[mf][q] = 0.f;
  #pragma unroll
  for (int mf = 0; mf < 4; mf++)
    #pragma unroll
    for (int nf = 0; nf < 4; nf++)
      #pragma unroll
      for (int q = 0; q < 4; q++) {
        float pp = __expf(acc2[mf][nf][q] - gmax[mf][q]);
        acc2[mf][nf][q] = pp;
        psum[mf][q] += pp;
      }
  #pragma unroll
  for (int mf = 0; mf < 4; mf++)
    #pragma unroll
    for (int q = 0; q < 4; q++) {
      float v = psum[mf][q];
      #pragma unroll
      for (int m = 1; m < 16; m <<= 1) v += __shfl_xor(v, m);
      psum[mf][q] = v;
    }
  if (lr == 0) {
    #pragma unroll
    for (int mf = 0; mf < 4; mf++)
      #pragma unroll
      for (int q = 0; q < 4; q++) red[1][w][mf * 16 + lq * 4 + q] = psum[mf][q];
  }
  BAR();

  // ---- gated atomic accumulate into y ----
  #pragma unroll
  for (int mf = 0; mf < 4; mf++) {
    #pragma unroll
    for (int q = 0; q < 4; q++) {
      int row = mf * 16 + lq * 4 + q;
      if (row < nvalid) {
        float ssum = 0.f;
        #pragma unroll
        for (int ww = 0; ww < 8; ww++) ssum += red[1][ww][row];
        float sc = gatearr[row] / ssum;
        int orow = rowarr[row] & 0xFFFF;
        float* yr = y + (size_t)orow * 512 + w * 64 + lr;
        #pragma unroll
        for (int nf = 0; nf < 4; nf++) {
          atomicAdd(yr + nf * 16, acc2[mf][nf][q] * sc);
        }
      }
    }
  }
}

// ---------------- launch ----------------
extern "C" void kernel_launch(void* const* d_in, const int* in_sizes, int n_in,
                              void* d_out, int out_size, void* d_ws, size_t ws_size,
                              hipStream_t stream) {
  (void)in_sizes; (void)n_in; (void)out_size; (void)ws_size;
  const float* x  = (const float*)d_in[0];
  const float* wg = (const float*)d_in[1];
  const float* w1 = (const float*)d_in[2];
  const float* b1 = (const float*)d_in[3];
  const float* w2 = (const float*)d_in[4];
  const float* b2 = (const float*)d_in[5];
  float* y = (float*)d_out;

  char* ws = (char*)d_ws;
  size_t off = 0;
  auto alloc = [&](size_t bytes) -> char* {
    char* p = ws + off;
    off += (bytes + 255) & ~(size_t)255;
    return p;
  };
  f16*   w1fr       = (f16*)  alloc((size_t)16 * 512 * 1024 * 2);
  f16*   w2fr       = (f16*)  alloc((size_t)16 * 1024 * 512 * 2);
  int*   tk_idx     = (int*)  alloc((size_t)16384 * 4 * 4);
  float* tk_gate    = (float*)alloc((size_t)16384 * 4 * 4);
  int*   rows_pk    = (int*)  alloc((size_t)16 * 16384 * 4);
  float* gates_l    = (float*)alloc((size_t)16 * 16384 * 4);
  int*   partial    = (int*)  alloc(16 * 64 * 4);
  int*   chunk_base = (int*)  alloc(16 * 64 * 4);
  int*   count      = (int*)  alloc(256);
  // total ~34.6 MB (known-safe)

  k_cvt_w1<<<dim3(4096), dim3(256), 0, stream>>>(w1, w1fr);
  k_cvt_w2<<<dim3(4096), dim3(256), 0, stream>>>(w2, w2fr);
  k_gate<<<dim3(4096), dim3(256), 0, stream>>>(x, wg, tk_idx, tk_gate);
  k_route_count<<<dim3(1024), dim3(256), 0, stream>>>(tk_idx, partial);
  k_route_scan<<<dim3(1), dim3(64), 0, stream>>>(partial, chunk_base, count);
  k_route_scatter<<<dim3(1024), dim3(256), 0, stream>>>(tk_idx, tk_gate, chunk_base,
                                                        rows_pk, gates_l);
  k_zero<<<dim3(8192), dim3(256), 0, stream>>>((float4*)y);
  k_expert<<<dim3(4096), dim3(512), 0, stream>>>(x, w1fr, w2fr, b1, b2,
                                                 count, rows_pk, gates_l, y);
}

// Round 17
// 372.246 us; speedup vs baseline: 1.0926x; 1.0926x over previous
//
#include <hip/hip_runtime.h>
#include <hip/hip_fp16.h>

typedef _Float16 f16;
typedef _Float16 f16x8 __attribute__((ext_vector_type(8)));
typedef float f32x4 __attribute__((ext_vector_type(4)));

#define MFMA(a,b,c) __builtin_amdgcn_mfma_f32_16x16x32_f16((a),(b),(c),0,0,0)

// raw barrier: drain LDS only; leave global loads in flight (no vmcnt(0))
#define BAR() do { \
  asm volatile("s_waitcnt lgkmcnt(0)" ::: "memory"); \
  __builtin_amdgcn_sched_barrier(0); \
  __builtin_amdgcn_s_barrier(); \
  __builtin_amdgcn_sched_barrier(0); \
} while (0)

// B=16384, IN=512, HID=1024, OUT=512, E=16, K=4
// ws: w1fr 16MB + w2fr 16MB + routing ~2.6MB = ~34.6MB (known-safe)

// w1: [16][512][1024] -> fragment fid=((e*64+n0)*16+kc), lane l, elem i
//   = w1[e][kc*32+(l>>4)*8+i][n0*16+(l&15)]
__global__ void k_cvt_w1(const float* __restrict__ w1, f16* __restrict__ w1fr) {
  int fid = blockIdx.x * 4 + (threadIdx.x >> 6);
  int l = threadIdx.x & 63;
  int e = fid >> 10, n0 = (fid >> 4) & 63, kc = fid & 15;
  int kbase = kc * 32 + (l >> 4) * 8;
  int col = n0 * 16 + (l & 15);
  const float* src = w1 + ((size_t)e * 512 + kbase) * 1024 + col;
  f16x8 o;
  #pragma unroll
  for (int i = 0; i < 8; i++) o[i] = (f16)src[(size_t)i * 1024];
  *(f16x8*)(w1fr + (size_t)fid * 512 + l * 8) = o;
}

// w2: [16][1024][512] -> frag fid=((e*32+n0)*32+kc)
__global__ void k_cvt_w2(const float* __restrict__ w2, f16* __restrict__ w2fr) {
  int fid = blockIdx.x * 4 + (threadIdx.x >> 6);
  int l = threadIdx.x & 63;
  int e = fid >> 10, n0 = (fid >> 5) & 31, kc = fid & 31;
  int kbase = kc * 32 + (l >> 4) * 8;
  int col = n0 * 16 + (l & 15);
  const float* src = w2 + ((size_t)e * 1024 + kbase) * 512 + col;
  f16x8 o;
  #pragma unroll
  for (int i = 0; i < 8; i++) o[i] = (f16)src[(size_t)i * 512];
  *(f16x8*)(w2fr + (size_t)fid * 512 + l * 8) = o;
}

// ---------------- gating ----------------
__global__ void k_gate(const float* __restrict__ x, const float* __restrict__ wg,
                       int* __restrict__ tk_idx, float* __restrict__ tk_gate) {
  int w = threadIdx.x >> 6, l = threadIdx.x & 63;
  int r = blockIdx.x * 4 + w;
  float p[16];
  #pragma unroll
  for (int e = 0; e < 16; e++) p[e] = 0.f;
  const float* xr = x + (size_t)r * 512;
  #pragma unroll
  for (int t = 0; t < 8; t++) {
    float xv = xr[t * 64 + l];
    const float* wrow = wg + (t * 64 + l) * 16;
    #pragma unroll
    for (int e = 0; e < 16; e++) p[e] += xv * wrow[e];
  }
  #pragma unroll
  for (int e = 0; e < 16; e++) {
    float v = p[e];
    #pragma unroll
    for (int m = 32; m >= 1; m >>= 1) v += __shfl_xor(v, m);
    p[e] = v;
  }
  unsigned chosen = 0;
  float bv[4]; int bi[4];
  #pragma unroll
  for (int j = 0; j < 4; j++) {
    float best = -3.4e38f; int be = 0;
    #pragma unroll
    for (int e = 0; e < 16; e++) {
      bool ok = !((chosen >> e) & 1u) && (p[e] > best);
      if (ok) { best = p[e]; be = e; }
    }
    chosen |= 1u << be; bv[j] = best; bi[j] = be;
  }
  float m0 = bv[0];
  float e0 = __expf(bv[0] - m0), e1 = __expf(bv[1] - m0),
        e2 = __expf(bv[2] - m0), e3 = __expf(bv[3] - m0);
  float s = e0 + e1 + e2 + e3;
  if (l == 0) {
    *(int4*)(tk_idx + (size_t)r * 4) = make_int4(bi[0], bi[1], bi[2], bi[3]);
    *(float4*)(tk_gate + (size_t)r * 4) = make_float4(e0 / s, e1 / s, e2 / s, e3 / s);
  }
}

// ---------------- routing (deterministic compaction) ----------------
__global__ void k_route_count(const int* __restrict__ tk_idx, int* __restrict__ partial) {
  int e = blockIdx.x >> 6, chunk = blockIdx.x & 63;
  int t = threadIdx.x;
  int row = chunk * 256 + t;
  int4 tk = ((const int4*)tk_idx)[row];
  bool match = (tk.x == e) || (tk.y == e) || (tk.z == e) || (tk.w == e);
  unsigned long long m = __ballot(match);
  __shared__ int wc[4];
  if ((t & 63) == 0) wc[t >> 6] = (int)__popcll(m);
  __syncthreads();
  if (t == 0) partial[e * 64 + chunk] = wc[0] + wc[1] + wc[2] + wc[3];
}

__global__ void k_route_scan(const int* __restrict__ partial, int* __restrict__ chunk_base,
                             int* __restrict__ count) {
  int l = threadIdx.x; // 64 threads
  for (int e = 0; e < 16; e++) {
    int v = partial[e * 64 + l];
    int orig = v;
    #pragma unroll
    for (int off = 1; off < 64; off <<= 1) {
      int u = __shfl_up(v, off);
      if (l >= off) v += u;
    }
    chunk_base[e * 64 + l] = v - orig;
    if (l == 63) count[e] = v;
  }
}

__global__ void k_route_scatter(const int* __restrict__ tk_idx, const float* __restrict__ tk_gate,
                                const int* __restrict__ chunk_base, int* __restrict__ rows_pk,
                                float* __restrict__ gates_l) {
  int e = blockIdx.x >> 6, chunk = blockIdx.x & 63;
  int t = threadIdx.x, w = t >> 6, l = t & 63;
  int row = chunk * 256 + t;
  int4 tk = ((const int4*)tk_idx)[row];
  int j = (tk.x == e) ? 0 : (tk.y == e) ? 1 : (tk.z == e) ? 2 : (tk.w == e) ? 3 : -1;
  bool match = (j >= 0);
  unsigned long long m = __ballot(match);
  __shared__ int wc[4];
  if (l == 0) wc[w] = (int)__popcll(m);
  __syncthreads();
  int wbase = 0;
  #pragma unroll
  for (int i = 0; i < 4; i++) if (i < w) wbase += wc[i];
  if (match) {
    int pos = (int)__popcll(m & ((1ULL << l) - 1ULL));
    int idx = e * 16384 + chunk_base[e * 64 + chunk] + wbase + pos;
    rows_pk[idx] = row | (j << 16);
    gates_l[idx] = tk_gate[(size_t)row * 4 + j];
  }
}

// ---------------- zero output ----------------
__global__ void k_zero(float4* __restrict__ y4) {
  y4[blockIdx.x * 256 + threadIdx.x] = make_float4(0.f, 0.f, 0.f, 0.f);
}

// ---------------- fused expert FFN: BM=64, 8 waves, deep static prefetch ----------------
// Small-acc design: stage-1 nf=2 (acc1=32 AGPR) -> acc total 96 (spill-free).
// Freed regs buy prefetch DEPTH: stage-1 depth-4 rotate (named slots, coverage ~4 steps
// >= L2 latency), stage-2 depth-2 x 4 frags. x resident 64KB seg-XOR; h 256-col chunks.
// lgkm-only BARs (12); K-loops barrier-free.
__global__ __launch_bounds__(512, 2) void k_expert(
    const float* __restrict__ x, const f16* __restrict__ w1fr, const f16* __restrict__ w2fr,
    const float* __restrict__ b1, const float* __restrict__ b2,
    const int* __restrict__ count, const int* __restrict__ rows_pk,
    const float* __restrict__ gates_l, float* __restrict__ y)
{
  int p = blockIdx.x;
  int xcd = p & 7, s = p >> 3;
  int e = (xcd << 1) | (s >> 8);
  int rb = s & 255;
  int cnt = count[e];
  int mstart = rb * 64;
  if (mstart >= cnt) return;
  int nvalid = cnt - mstart; if (nvalid > 64) nvalid = 64;

  __shared__ f16 x_lds[64 * 512];   // 64KB, staged once, seg-XOR swizzled (mask 63)
  __shared__ f16 h_lds[64 * 256];   // 32KB (256-col hc chunk), seg-XOR (mask 31)
  __shared__ int rowarr[64];
  __shared__ float gatearr[64];
  __shared__ float red[2][8][64];   // 4KB

  int t = threadIdx.x, w = t >> 6, l = t & 63;
  int lq = l >> 4, lr = l & 15;

  if (t < 64) {
    int idx = (t < nvalid) ? t : (nvalid - 1);
    int src = e * 16384 + mstart + idx;
    rowarr[t] = rows_pk[src];
    gatearr[t] = gates_l[src];
  }
  BAR();

  char* xb = (char*)x_lds;
  char* hb = (char*)h_lds;

  // ---- stage x once: 8 threads/row, 8 segs (16B) each ----
  {
    int srow = t >> 3, sj = t & 7;
    const float* sp = x + (size_t)(rowarr[srow] & 0xFFFF) * 512;
    #pragma unroll
    for (int j = 0; j < 8; j++) {
      int seg = sj + j * 8;                       // 0..63
      const float* qp = sp + seg * 8;
      float4 u0 = ((const float4*)qp)[0], u1 = ((const float4*)qp)[1];
      f16x8 v;
      v[0]=(f16)u0.x; v[1]=(f16)u0.y; v[2]=(f16)u0.z; v[3]=(f16)u0.w;
      v[4]=(f16)u1.x; v[5]=(f16)u1.y; v[6]=(f16)u1.z; v[7]=(f16)u1.w;
      int byte = srow * 1024 + ((seg ^ srow) & 63) * 16;
      *(f16x8*)(xb + byte) = v;
    }
  }
  BAR();   // x ready (read-only afterwards)

  const f16x8* w1f8 = (const f16x8*)w1fr;
  const f16x8* w2f8 = (const f16x8*)w2fr;

  f32x4 acc2[4][4];   // rows mf*16+lq*4+q, cols w*64+nf*16+lr
  #pragma unroll
  for (int a = 0; a < 4; a++)
    #pragma unroll
    for (int b = 0; b < 4; b++)
      #pragma unroll
      for (int q = 0; q < 4; q++) acc2[a][b][q] = 0.f;

  #pragma unroll 1
  for (int hc = 0; hc < 4; hc++) {
    // ---- stage 1: h[:, hc*256 + (w*2+nf)*16+lr] = x @ w1, K=512, 16 steps ----
    // depth-4 named-slot prefetch: wA..wD each hold {nf0,nf1} for one kcg step.
    f32x4 acc1[4][2];
    #pragma unroll
    for (int a = 0; a < 4; a++)
      #pragma unroll
      for (int b = 0; b < 2; b++)
        #pragma unroll
        for (int q = 0; q < 4; q++) acc1[a][b][q] = 0.f;

    const f16x8* bp1 = w1f8 + ((size_t)((e * 64 + hc * 16 + w * 2) * 16)) * 64 + l;
    #define LD1(dst, k) { dst[0] = bp1[(k) * 64]; dst[1] = bp1[16 * 64 + (k) * 64]; }
    #define ST1(slot, kk) { \
      int seg = (kk) * 4 + lq; \
      f16x8 av0 = *(const f16x8*)(xb + (lr) * 1024 + ((seg ^ lr) & 63) * 16); \
      f16x8 av1 = *(const f16x8*)(xb + (16 + lr) * 1024 + ((seg ^ (16 + lr)) & 63) * 16); \
      f16x8 av2 = *(const f16x8*)(xb + (32 + lr) * 1024 + ((seg ^ (32 + lr)) & 63) * 16); \
      f16x8 av3 = *(const f16x8*)(xb + (48 + lr) * 1024 + ((seg ^ (48 + lr)) & 63) * 16); \
      acc1[0][0] = MFMA(av0, slot[0], acc1[0][0]); \
      acc1[0][1] = MFMA(av0, slot[1], acc1[0][1]); \
      acc1[1][0] = MFMA(av1, slot[0], acc1[1][0]); \
      acc1[1][1] = MFMA(av1, slot[1], acc1[1][1]); \
      acc1[2][0] = MFMA(av2, slot[0], acc1[2][0]); \
      acc1[2][1] = MFMA(av2, slot[1], acc1[2][1]); \
      acc1[3][0] = MFMA(av3, slot[0], acc1[3][0]); \
      acc1[3][1] = MFMA(av3, slot[1], acc1[3][1]); \
    }
    f16x8 wA[2], wB[2], wC[2], wD[2];
    LD1(wA, 0) LD1(wB, 1) LD1(wC, 2) LD1(wD, 3)
    #pragma unroll 1
    for (int j = 0; j < 4; j++) {
      int kb = j * 4;
      ST1(wA, kb + 0); if (j < 3) LD1(wA, kb + 4);
      ST1(wB, kb + 1); if (j < 3) LD1(wB, kb + 5);
      ST1(wC, kb + 2); if (j < 3) LD1(wC, kb + 6);
      ST1(wD, kb + 3); if (j < 3) LD1(wD, kb + 7);
    }
    #undef LD1
    #undef ST1

    BAR();   // prev hc's stage-2 h reads complete before overwrite
    // ---- h epilogue: bias + relu -> h_lds (chunk cols cc = w*32+nf*16+lr) ----
    #pragma unroll
    for (int nf = 0; nf < 2; nf++) {
      int cc = w * 32 + nf * 16 + lr;
      float bv = b1[e * 1024 + hc * 256 + cc];
      int segw = cc >> 3;
      int inb = (cc & 7) * 2;
      #pragma unroll
      for (int mf = 0; mf < 4; mf++)
        #pragma unroll
        for (int q = 0; q < 4; q++) {
          int row = mf * 16 + lq * 4 + q;
          float hv = fmaxf(acc1[mf][nf][q] + bv, 0.f);
          int byte = row * 512 + ((segw ^ (row & 31)) & 31) * 16 + inb;
          *(f16*)(hb + byte) = (f16)hv;
        }
    }
    BAR();   // h ready

    // ---- stage 2: acc2 += h_chunk @ w2, K=256, 8 steps, depth-2 x 4 frags ----
    const f16x8* bp2 = w2f8 + ((size_t)((e * 32 + w * 4) * 32 + hc * 8)) * 64 + l;
    #define LD2(dst, k) { \
      dst[0] = bp2[(k) * 64]; \
      dst[1] = bp2[32 * 64 + (k) * 64]; \
      dst[2] = bp2[64 * 64 + (k) * 64]; \
      dst[3] = bp2[96 * 64 + (k) * 64]; \
    }
    #define ST2(slot, kk) { \
      int seg = (kk) * 4 + lq; \
      f16x8 av0 = *(const f16x8*)(hb + (lr) * 512 + (((seg) ^ (lr & 31)) & 31) * 16); \
      f16x8 av1 = *(const f16x8*)(hb + (16 + lr) * 512 + (((seg) ^ ((16 + lr) & 31)) & 31) * 16); \
      f16x8 av2 = *(const f16x8*)(hb + (32 + lr) * 512 + (((seg) ^ ((32 + lr) & 31)) & 31) * 16); \
      f16x8 av3 = *(const f16x8*)(hb + (48 + lr) * 512 + (((seg) ^ ((48 + lr) & 31)) & 31) * 16); \
      acc2[0][0] = MFMA(av0, slot[0], acc2[0][0]); \
      acc2[0][1] = MFMA(av0, slot[1], acc2[0][1]); \
      acc2[0][2] = MFMA(av0, slot[2], acc2[0][2]); \
      acc2[0][3] = MFMA(av0, slot[3], acc2[0][3]); \
      acc2[1][0] = MFMA(av1, slot[0], acc2[1][0]); \
      acc2[1][1] = MFMA(av1, slot[1], acc2[1][1]); \
      acc2[1][2] = MFMA(av1, slot[2], acc2[1][2]); \
      acc2[1][3] = MFMA(av1, slot[3], acc2[1][3]); \
      acc2[2][0] = MFMA(av2, slot[0], acc2[2][0]); \
      acc2[2][1] = MFMA(av2, slot[1], acc2[2][1]); \
      acc2[2][2] = MFMA(av2, slot[2], acc2[2][2]); \
      acc2[2][3] = MFMA(av2, slot[3], acc2[2][3]); \
      acc2[3][0] = MFMA(av3, slot[0], acc2[3][0]); \
      acc2[3][1] = MFMA(av3, slot[1], acc2[3][1]); \
      acc2[3][2] = MFMA(av3, slot[2], acc2[3][2]); \
      acc2[3][3] = MFMA(av3, slot[3], acc2[3][3]); \
    }
    f16x8 uA[4], uB[4];
    LD2(uA, 0) LD2(uB, 1)
    #pragma unroll 1
    for (int j = 0; j < 4; j++) {
      int kb = j * 2;
      ST2(uA, kb + 0); if (j < 3) LD2(uA, kb + 2);
      ST2(uB, kb + 1); if (j < 3) LD2(uB, kb + 3);
    }
    #undef LD2
    #undef ST2
  }

  // bias2: cols w*64 + nf*16 + lr
  #pragma unroll
  for (int nf = 0; nf < 4; nf++) {
    float bv = b2[e * 512 + w * 64 + nf * 16 + lr];
    #pragma unroll
    for (int mf = 0; mf < 4; mf++)
      #pragma unroll
      for (int q = 0; q < 4; q++) acc2[mf][nf][q] += bv;
  }

  // ---- softmax across full row (512 cols over 8 waves) ----
  float rmax[4][4];
  #pragma unroll
  for (int mf = 0; mf < 4; mf++)
    #pragma unroll
    for (int q = 0; q < 4; q++) {
      float v = acc2[mf][0][q];
      #pragma unroll
      for (int nf = 1; nf < 4; nf++) v = fmaxf(v, acc2[mf][nf][q]);
      #pragma unroll
      for (int m = 1; m < 16; m <<= 1) v = fmaxf(v, __shfl_xor(v, m));
      rmax[mf][q] = v;
    }
  if (lr == 0) {
    #pragma unroll
    for (int mf = 0; mf < 4; mf++)
      #pragma unroll
      for (int q = 0; q < 4; q++) red[0][w][mf * 16 + lq * 4 + q] = rmax[mf][q];
  }
  BAR();
  float gmax[4][4];
  #pragma unroll
  for (int mf = 0; mf < 4; mf++)
    #pragma unroll
    for (int q = 0; q < 4; q++) {
      int row = mf * 16 + lq * 4 + q;
      float v = red[0][0][row];
      #pragma unroll
      for (int ww = 1; ww < 8; ww++) v = fmaxf(v, red[0][ww][row]);
      gmax[mf][q] = v;
    }
  float psum[4][4];
  #pragma unroll
  for (int mf = 0; mf < 4; mf++)
    #pragma unroll
    for (int q = 0; q < 4; q++) psum[mf][q] = 0.f;
  #pragma unroll
  for (int mf = 0; mf < 4; mf++)
    #pragma unroll
    for (int nf = 0; nf < 4; nf++)
      #pragma unroll
      for (int q = 0; q < 4; q++) {
        float pp = __expf(acc2[mf][nf][q] - gmax[mf][q]);
        acc2[mf][nf][q] = pp;
        psum[mf][q] += pp;
      }
  #pragma unroll
  for (int mf = 0; mf < 4; mf++)
    #pragma unroll
    for (int q = 0; q < 4; q++) {
      float v = psum[mf][q];
      #pragma unroll
      for (int m = 1; m < 16; m <<= 1) v += __shfl_xor(v, m);
      psum[mf][q] = v;
    }
  if (lr == 0) {
    #pragma unroll
    for (int mf = 0; mf < 4; mf++)
      #pragma unroll
      for (int q = 0; q < 4; q++) red[1][w][mf * 16 + lq * 4 + q] = psum[mf][q];
  }
  BAR();

  // ---- gated atomic accumulate into y ----
  #pragma unroll
  for (int mf = 0; mf < 4; mf++) {
    #pragma unroll
    for (int q = 0; q < 4; q++) {
      int row = mf * 16 + lq * 4 + q;
      if (row < nvalid) {
        float ssum = 0.f;
        #pragma unroll
        for (int ww = 0; ww < 8; ww++) ssum += red[1][ww][row];
        float sc = gatearr[row] / ssum;
        int orow = rowarr[row] & 0xFFFF;
        float* yr = y + (size_t)orow * 512 + w * 64 + lr;
        #pragma unroll
        for (int nf = 0; nf < 4; nf++) {
          atomicAdd(yr + nf * 16, acc2[mf][nf][q] * sc);
        }
      }
    }
  }
}

// ---------------- launch ----------------
extern "C" void kernel_launch(void* const* d_in, const int* in_sizes, int n_in,
                              void* d_out, int out_size, void* d_ws, size_t ws_size,
                              hipStream_t stream) {
  (void)in_sizes; (void)n_in; (void)out_size; (void)ws_size;
  const float* x  = (const float*)d_in[0];
  const float* wg = (const float*)d_in[1];
  const float* w1 = (const float*)d_in[2];
  const float* b1 = (const float*)d_in[3];
  const float* w2 = (const float*)d_in[4];
  const float* b2 = (const float*)d_in[5];
  float* y = (float*)d_out;

  char* ws = (char*)d_ws;
  size_t off = 0;
  auto alloc = [&](size_t bytes) -> char* {
    char* p = ws + off;
    off += (bytes + 255) & ~(size_t)255;
    return p;
  };
  f16*   w1fr       = (f16*)  alloc((size_t)16 * 512 * 1024 * 2);
  f16*   w2fr       = (f16*)  alloc((size_t)16 * 1024 * 512 * 2);
  int*   tk_idx     = (int*)  alloc((size_t)16384 * 4 * 4);
  float* tk_gate    = (float*)alloc((size_t)16384 * 4 * 4);
  int*   rows_pk    = (int*)  alloc((size_t)16 * 16384 * 4);
  float* gates_l    = (float*)alloc((size_t)16 * 16384 * 4);
  int*   partial    = (int*)  alloc(16 * 64 * 4);
  int*   chunk_base = (int*)  alloc(16 * 64 * 4);
  int*   count      = (int*)  alloc(256);
  // total ~34.6 MB (known-safe)

  k_cvt_w1<<<dim3(4096), dim3(256), 0, stream>>>(w1, w1fr);
  k_cvt_w2<<<dim3(4096), dim3(256), 0, stream>>>(w2, w2fr);
  k_gate<<<dim3(4096), dim3(256), 0, stream>>>(x, wg, tk_idx, tk_gate);
  k_route_count<<<dim3(1024), dim3(256), 0, stream>>>(tk_idx, partial);
  k_route_scan<<<dim3(1), dim3(64), 0, stream>>>(partial, chunk_base, count);
  k_route_scatter<<<dim3(1024), dim3(256), 0, stream>>>(tk_idx, tk_gate, chunk_base,
                                                        rows_pk, gates_l);
  k_zero<<<dim3(8192), dim3(256), 0, stream>>>((float4*)y);
  k_expert<<<dim3(4096), dim3(512), 0, stream>>>(x, w1fr, w2fr, b1, b2,
                                                 count, rows_pk, gates_l, y);
}

// Round 18
// 364.328 us; speedup vs baseline: 1.1164x; 1.0217x over previous
//
#include <hip/hip_runtime.h>
#include <hip/hip_fp16.h>

typedef _Float16 f16;
typedef _Float16 f16x8 __attribute__((ext_vector_type(8)));
typedef float f32x4 __attribute__((ext_vector_type(4)));

#define MFMA(a,b,c) __builtin_amdgcn_mfma_f32_16x16x32_f16((a),(b),(c),0,0,0)

// raw barrier: drain LDS only; leave global loads in flight (no vmcnt(0))
#define BAR() do { \
  asm volatile("s_waitcnt lgkmcnt(0)" ::: "memory"); \
  __builtin_amdgcn_sched_barrier(0); \
  __builtin_amdgcn_s_barrier(); \
  __builtin_amdgcn_sched_barrier(0); \
} while (0)

// B=16384, IN=512, HID=1024, OUT=512, E=16, K=4
// ws: w1fr 16MB + w2fr 16MB + routing ~2.6MB = ~34.6MB (known-safe)

// w1: [16][512][1024] -> fragment fid=((e*64+n0)*16+kc), lane l, elem i
//   = w1[e][kc*32+(l>>4)*8+i][n0*16+(l&15)]
__global__ void k_cvt_w1(const float* __restrict__ w1, f16* __restrict__ w1fr) {
  int fid = blockIdx.x * 4 + (threadIdx.x >> 6);
  int l = threadIdx.x & 63;
  int e = fid >> 10, n0 = (fid >> 4) & 63, kc = fid & 15;
  int kbase = kc * 32 + (l >> 4) * 8;
  int col = n0 * 16 + (l & 15);
  const float* src = w1 + ((size_t)e * 512 + kbase) * 1024 + col;
  f16x8 o;
  #pragma unroll
  for (int i = 0; i < 8; i++) o[i] = (f16)src[(size_t)i * 1024];
  *(f16x8*)(w1fr + (size_t)fid * 512 + l * 8) = o;
}

// w2: [16][1024][512] -> frag fid=((e*32+n0)*32+kc)
__global__ void k_cvt_w2(const float* __restrict__ w2, f16* __restrict__ w2fr) {
  int fid = blockIdx.x * 4 + (threadIdx.x >> 6);
  int l = threadIdx.x & 63;
  int e = fid >> 10, n0 = (fid >> 5) & 31, kc = fid & 31;
  int kbase = kc * 32 + (l >> 4) * 8;
  int col = n0 * 16 + (l & 15);
  const float* src = w2 + ((size_t)e * 1024 + kbase) * 512 + col;
  f16x8 o;
  #pragma unroll
  for (int i = 0; i < 8; i++) o[i] = (f16)src[(size_t)i * 512];
  *(f16x8*)(w2fr + (size_t)fid * 512 + l * 8) = o;
}

// ---------------- gating ----------------
__global__ void k_gate(const float* __restrict__ x, const float* __restrict__ wg,
                       int* __restrict__ tk_idx, float* __restrict__ tk_gate) {
  int w = threadIdx.x >> 6, l = threadIdx.x & 63;
  int r = blockIdx.x * 4 + w;
  float p[16];
  #pragma unroll
  for (int e = 0; e < 16; e++) p[e] = 0.f;
  const float* xr = x + (size_t)r * 512;
  #pragma unroll
  for (int t = 0; t < 8; t++) {
    float xv = xr[t * 64 + l];
    const float* wrow = wg + (t * 64 + l) * 16;
    #pragma unroll
    for (int e = 0; e < 16; e++) p[e] += xv * wrow[e];
  }
  #pragma unroll
  for (int e = 0; e < 16; e++) {
    float v = p[e];
    #pragma unroll
    for (int m = 32; m >= 1; m >>= 1) v += __shfl_xor(v, m);
    p[e] = v;
  }
  unsigned chosen = 0;
  float bv[4]; int bi[4];
  #pragma unroll
  for (int j = 0; j < 4; j++) {
    float best = -3.4e38f; int be = 0;
    #pragma unroll
    for (int e = 0; e < 16; e++) {
      bool ok = !((chosen >> e) & 1u) && (p[e] > best);
      if (ok) { best = p[e]; be = e; }
    }
    chosen |= 1u << be; bv[j] = best; bi[j] = be;
  }
  float m0 = bv[0];
  float e0 = __expf(bv[0] - m0), e1 = __expf(bv[1] - m0),
        e2 = __expf(bv[2] - m0), e3 = __expf(bv[3] - m0);
  float s = e0 + e1 + e2 + e3;
  if (l == 0) {
    *(int4*)(tk_idx + (size_t)r * 4) = make_int4(bi[0], bi[1], bi[2], bi[3]);
    *(float4*)(tk_gate + (size_t)r * 4) = make_float4(e0 / s, e1 / s, e2 / s, e3 / s);
  }
}

// ---------------- routing (deterministic compaction) ----------------
__global__ void k_route_count(const int* __restrict__ tk_idx, int* __restrict__ partial) {
  int e = blockIdx.x >> 6, chunk = blockIdx.x & 63;
  int t = threadIdx.x;
  int row = chunk * 256 + t;
  int4 tk = ((const int4*)tk_idx)[row];
  bool match = (tk.x == e) || (tk.y == e) || (tk.z == e) || (tk.w == e);
  unsigned long long m = __ballot(match);
  __shared__ int wc[4];
  if ((t & 63) == 0) wc[t >> 6] = (int)__popcll(m);
  __syncthreads();
  if (t == 0) partial[e * 64 + chunk] = wc[0] + wc[1] + wc[2] + wc[3];
}

__global__ void k_route_scan(const int* __restrict__ partial, int* __restrict__ chunk_base,
                             int* __restrict__ count) {
  int l = threadIdx.x; // 64 threads
  for (int e = 0; e < 16; e++) {
    int v = partial[e * 64 + l];
    int orig = v;
    #pragma unroll
    for (int off = 1; off < 64; off <<= 1) {
      int u = __shfl_up(v, off);
      if (l >= off) v += u;
    }
    chunk_base[e * 64 + l] = v - orig;
    if (l == 63) count[e] = v;
  }
}

__global__ void k_route_scatter(const int* __restrict__ tk_idx, const float* __restrict__ tk_gate,
                                const int* __restrict__ chunk_base, int* __restrict__ rows_pk,
                                float* __restrict__ gates_l) {
  int e = blockIdx.x >> 6, chunk = blockIdx.x & 63;
  int t = threadIdx.x, w = t >> 6, l = t & 63;
  int row = chunk * 256 + t;
  int4 tk = ((const int4*)tk_idx)[row];
  int j = (tk.x == e) ? 0 : (tk.y == e) ? 1 : (tk.z == e) ? 2 : (tk.w == e) ? 3 : -1;
  bool match = (j >= 0);
  unsigned long long m = __ballot(match);
  __shared__ int wc[4];
  if (l == 0) wc[w] = (int)__popcll(m);
  __syncthreads();
  int wbase = 0;
  #pragma unroll
  for (int i = 0; i < 4; i++) if (i < w) wbase += wc[i];
  if (match) {
    int pos = (int)__popcll(m & ((1ULL << l) - 1ULL));
    int idx = e * 16384 + chunk_base[e * 64 + chunk] + wbase + pos;
    rows_pk[idx] = row | (j << 16);
    gates_l[idx] = tk_gate[(size_t)row * 4 + j];
  }
}

// ---------------- zero output ----------------
__global__ void k_zero(float4* __restrict__ y4) {
  y4[blockIdx.x * 256 + threadIdx.x] = make_float4(0.f, 0.f, 0.f, 0.f);
}

// ---------------- fused expert FFN: BM=64, 8 waves, dual-pipeline (weights + A-operand) ----
// R17 (spill-free, 0-conflict, x-resident) + A-operand register double-buffer:
// per step the NEXT step's 4 ds_read_b128 are issued before this step's MFMA cluster,
// so ~120cy LDS latency hides under MFMA issue. Weight rotation depth-4 (stage1) /
// depth-2 (stage2) unchanged. Live regs ~200 <= 256 -> no spill by construction.
__global__ __launch_bounds__(512, 2) void k_expert(
    const float* __restrict__ x, const f16* __restrict__ w1fr, const f16* __restrict__ w2fr,
    const float* __restrict__ b1, const float* __restrict__ b2,
    const int* __restrict__ count, const int* __restrict__ rows_pk,
    const float* __restrict__ gates_l, float* __restrict__ y)
{
  int p = blockIdx.x;
  int xcd = p & 7, s = p >> 3;
  int e = (xcd << 1) | (s >> 8);
  int rb = s & 255;
  int cnt = count[e];
  int mstart = rb * 64;
  if (mstart >= cnt) return;
  int nvalid = cnt - mstart; if (nvalid > 64) nvalid = 64;

  __shared__ f16 x_lds[64 * 512];   // 64KB, staged once, seg-XOR swizzled (mask 63)
  __shared__ f16 h_lds[64 * 256];   // 32KB (256-col hc chunk), seg-XOR (mask 31)
  __shared__ int rowarr[64];
  __shared__ float gatearr[64];
  __shared__ float red[2][8][64];   // 4KB

  int t = threadIdx.x, w = t >> 6, l = t & 63;
  int lq = l >> 4, lr = l & 15;

  if (t < 64) {
    int idx = (t < nvalid) ? t : (nvalid - 1);
    int src = e * 16384 + mstart + idx;
    rowarr[t] = rows_pk[src];
    gatearr[t] = gates_l[src];
  }
  BAR();

  char* xb = (char*)x_lds;
  char* hb = (char*)h_lds;

  // ---- stage x once: 8 threads/row, 8 segs (16B) each ----
  {
    int srow = t >> 3, sj = t & 7;
    const float* sp = x + (size_t)(rowarr[srow] & 0xFFFF) * 512;
    #pragma unroll
    for (int j = 0; j < 8; j++) {
      int seg = sj + j * 8;                       // 0..63
      const float* qp = sp + seg * 8;
      float4 u0 = ((const float4*)qp)[0], u1 = ((const float4*)qp)[1];
      f16x8 v;
      v[0]=(f16)u0.x; v[1]=(f16)u0.y; v[2]=(f16)u0.z; v[3]=(f16)u0.w;
      v[4]=(f16)u1.x; v[5]=(f16)u1.y; v[6]=(f16)u1.z; v[7]=(f16)u1.w;
      int byte = srow * 1024 + ((seg ^ srow) & 63) * 16;
      *(f16x8*)(xb + byte) = v;
    }
  }
  BAR();   // x ready (read-only afterwards)

  const f16x8* w1f8 = (const f16x8*)w1fr;
  const f16x8* w2f8 = (const f16x8*)w2fr;

  f32x4 acc2[4][4];   // rows mf*16+lq*4+q, cols w*64+nf*16+lr
  #pragma unroll
  for (int a = 0; a < 4; a++)
    #pragma unroll
    for (int b = 0; b < 4; b++)
      #pragma unroll
      for (int q = 0; q < 4; q++) acc2[a][b][q] = 0.f;

  #pragma unroll 1
  for (int hc = 0; hc < 4; hc++) {
    // ---- stage 1: h[:, hc*256 + (w*2+nf)*16+lr] = x @ w1, K=512, 16 steps ----
    f32x4 acc1[4][2];
    #pragma unroll
    for (int a = 0; a < 4; a++)
      #pragma unroll
      for (int b = 0; b < 2; b++)
        #pragma unroll
        for (int q = 0; q < 4; q++) acc1[a][b][q] = 0.f;

    const f16x8* bp1 = w1f8 + ((size_t)((e * 64 + hc * 16 + w * 2) * 16)) * 64 + l;
    #define LD1(dst, k) { dst[0] = bp1[(k) * 64]; dst[1] = bp1[16 * 64 + (k) * 64]; }
    #define LDAV1(dst, kk) { \
      int seg = (kk) * 4 + lq; \
      dst[0] = *(const f16x8*)(xb + (lr) * 1024 + (((seg) ^ lr) & 63) * 16); \
      dst[1] = *(const f16x8*)(xb + (16 + lr) * 1024 + (((seg) ^ (16 + lr)) & 63) * 16); \
      dst[2] = *(const f16x8*)(xb + (32 + lr) * 1024 + (((seg) ^ (32 + lr)) & 63) * 16); \
      dst[3] = *(const f16x8*)(xb + (48 + lr) * 1024 + (((seg) ^ (48 + lr)) & 63) * 16); \
    }
    #define FMA1(av, slot) { \
      acc1[0][0] = MFMA(av[0], slot[0], acc1[0][0]); \
      acc1[0][1] = MFMA(av[0], slot[1], acc1[0][1]); \
      acc1[1][0] = MFMA(av[1], slot[0], acc1[1][0]); \
      acc1[1][1] = MFMA(av[1], slot[1], acc1[1][1]); \
      acc1[2][0] = MFMA(av[2], slot[0], acc1[2][0]); \
      acc1[2][1] = MFMA(av[2], slot[1], acc1[2][1]); \
      acc1[3][0] = MFMA(av[3], slot[0], acc1[3][0]); \
      acc1[3][1] = MFMA(av[3], slot[1], acc1[3][1]); \
    }
    f16x8 wA[2], wB[2], wC[2], wD[2];
    f16x8 avA[4], avB[4];
    LD1(wA, 0) LD1(wB, 1) LD1(wC, 2) LD1(wD, 3)
    LDAV1(avA, 0)
    #pragma unroll 1
    for (int jj = 0; jj < 4; jj++) {
      int kb = jj * 4;
      LDAV1(avB, kb + 1); FMA1(avA, wA); if (jj < 3) LD1(wA, kb + 4);
      LDAV1(avA, kb + 2); FMA1(avB, wB); if (jj < 3) LD1(wB, kb + 5);
      LDAV1(avB, kb + 3); FMA1(avA, wC); if (jj < 3) LD1(wC, kb + 6);
      if (jj < 3) LDAV1(avA, kb + 4);
      FMA1(avB, wD); if (jj < 3) LD1(wD, kb + 7);
    }
    #undef LD1
    #undef LDAV1
    #undef FMA1

    BAR();   // prev hc's stage-2 h reads complete before overwrite
    // ---- h epilogue: bias + relu -> h_lds (chunk cols cc = w*32+nf*16+lr) ----
    #pragma unroll
    for (int nf = 0; nf < 2; nf++) {
      int cc = w * 32 + nf * 16 + lr;
      float bv = b1[e * 1024 + hc * 256 + cc];
      int segw = cc >> 3;
      int inb = (cc & 7) * 2;
      #pragma unroll
      for (int mf = 0; mf < 4; mf++)
        #pragma unroll
        for (int q = 0; q < 4; q++) {
          int row = mf * 16 + lq * 4 + q;
          float hv = fmaxf(acc1[mf][nf][q] + bv, 0.f);
          int byte = row * 512 + ((segw ^ (row & 31)) & 31) * 16 + inb;
          *(f16*)(hb + byte) = (f16)hv;
        }
    }
    BAR();   // h ready

    // ---- stage 2: acc2 += h_chunk @ w2, K=256, 8 steps, weights depth-2, av dbuf ----
    const f16x8* bp2 = w2f8 + ((size_t)((e * 32 + w * 4) * 32 + hc * 8)) * 64 + l;
    #define LD2(dst, k) { \
      dst[0] = bp2[(k) * 64]; \
      dst[1] = bp2[32 * 64 + (k) * 64]; \
      dst[2] = bp2[64 * 64 + (k) * 64]; \
      dst[3] = bp2[96 * 64 + (k) * 64]; \
    }
    #define LDAV2(dst, kk) { \
      int seg = (kk) * 4 + lq; \
      dst[0] = *(const f16x8*)(hb + (lr) * 512 + (((seg) ^ (lr & 31)) & 31) * 16); \
      dst[1] = *(const f16x8*)(hb + (16 + lr) * 512 + (((seg) ^ ((16 + lr) & 31)) & 31) * 16); \
      dst[2] = *(const f16x8*)(hb + (32 + lr) * 512 + (((seg) ^ ((32 + lr) & 31)) & 31) * 16); \
      dst[3] = *(const f16x8*)(hb + (48 + lr) * 512 + (((seg) ^ ((48 + lr) & 31)) & 31) * 16); \
    }
    #define FMA2(av, slot) { \
      acc2[0][0] = MFMA(av[0], slot[0], acc2[0][0]); \
      acc2[0][1] = MFMA(av[0], slot[1], acc2[0][1]); \
      acc2[0][2] = MFMA(av[0], slot[2], acc2[0][2]); \
      acc2[0][3] = MFMA(av[0], slot[3], acc2[0][3]); \
      acc2[1][0] = MFMA(av[1], slot[0], acc2[1][0]); \
      acc2[1][1] = MFMA(av[1], slot[1], acc2[1][1]); \
      acc2[1][2] = MFMA(av[1], slot[2], acc2[1][2]); \
      acc2[1][3] = MFMA(av[1], slot[3], acc2[1][3]); \
      acc2[2][0] = MFMA(av[2], slot[0], acc2[2][0]); \
      acc2[2][1] = MFMA(av[2], slot[1], acc2[2][1]); \
      acc2[2][2] = MFMA(av[2], slot[2], acc2[2][2]); \
      acc2[2][3] = MFMA(av[2], slot[3], acc2[2][3]); \
      acc2[3][0] = MFMA(av[3], slot[0], acc2[3][0]); \
      acc2[3][1] = MFMA(av[3], slot[1], acc2[3][1]); \
      acc2[3][2] = MFMA(av[3], slot[2], acc2[3][2]); \
      acc2[3][3] = MFMA(av[3], slot[3], acc2[3][3]); \
    }
    f16x8 uA[4], uB[4];
    f16x8 hvA[4], hvB[4];
    LD2(uA, 0) LD2(uB, 1)
    LDAV2(hvA, 0)
    #pragma unroll 1
    for (int jj = 0; jj < 4; jj++) {
      int kb = jj * 2;
      LDAV2(hvB, kb + 1); FMA2(hvA, uA); if (jj < 3) LD2(uA, kb + 2);
      if (jj < 3) LDAV2(hvA, kb + 2);
      FMA2(hvB, uB); if (jj < 3) LD2(uB, kb + 3);
    }
    #undef LD2
    #undef LDAV2
    #undef FMA2
  }

  // bias2: cols w*64 + nf*16 + lr
  #pragma unroll
  for (int nf = 0; nf < 4; nf++) {
    float bv = b2[e * 512 + w * 64 + nf * 16 + lr];
    #pragma unroll
    for (int mf = 0; mf < 4; mf++)
      #pragma unroll
      for (int q = 0; q < 4; q++) acc2[mf][nf][q] += bv;
  }

  // ---- softmax across full row (512 cols over 8 waves) ----
  float rmax[4][4];
  #pragma unroll
  for (int mf = 0; mf < 4; mf++)
    #pragma unroll
    for (int q = 0; q < 4; q++) {
      float v = acc2[mf][0][q];
      #pragma unroll
      for (int nf = 1; nf < 4; nf++) v = fmaxf(v, acc2[mf][nf][q]);
      #pragma unroll
      for (int m = 1; m < 16; m <<= 1) v = fmaxf(v, __shfl_xor(v, m));
      rmax[mf][q] = v;
    }
  if (lr == 0) {
    #pragma unroll
    for (int mf = 0; mf < 4; mf++)
      #pragma unroll
      for (int q = 0; q < 4; q++) red[0][w][mf * 16 + lq * 4 + q] = rmax[mf][q];
  }
  BAR();
  float gmax[4][4];
  #pragma unroll
  for (int mf = 0; mf < 4; mf++)
    #pragma unroll
    for (int q = 0; q < 4; q++) {
      int row = mf * 16 + lq * 4 + q;
      float v = red[0][0][row];
      #pragma unroll
      for (int ww = 1; ww < 8; ww++) v = fmaxf(v, red[0][ww][row]);
      gmax[mf][q] = v;
    }
  float psum[4][4];
  #pragma unroll
  for (int mf = 0; mf < 4; mf++)
    #pragma unroll
    for (int q = 0; q < 4; q++) psum[mf][q] = 0.f;
  #pragma unroll
  for (int mf = 0; mf < 4; mf++)
    #pragma unroll
    for (int nf = 0; nf < 4; nf++)
      #pragma unroll
      for (int q = 0; q < 4; q++) {
        float pp = __expf(acc2[mf][nf][q] - gmax[mf][q]);
        acc2[mf][nf][q] = pp;
        psum[mf][q] += pp;
      }
  #pragma unroll
  for (int mf = 0; mf < 4; mf++)
    #pragma unroll
    for (int q = 0; q < 4; q++) {
      float v = psum[mf][q];
      #pragma unroll
      for (int m = 1; m < 16; m <<= 1) v += __shfl_xor(v, m);
      psum[mf][q] = v;
    }
  if (lr == 0) {
    #pragma unroll
    for (int mf = 0; mf < 4; mf++)
      #pragma unroll
      for (int q = 0; q < 4; q++) red[1][w][mf * 16 + lq * 4 + q] = psum[mf][q];
  }
  BAR();

  // ---- gated atomic accumulate into y ----
  #pragma unroll
  for (int mf = 0; mf < 4; mf++) {
    #pragma unroll
    for (int q = 0; q < 4; q++) {
      int row = mf * 16 + lq * 4 + q;
      if (row < nvalid) {
        float ssum = 0.f;
        #pragma unroll
        for (int ww = 0; ww < 8; ww++) ssum += red[1][ww][row];
        float sc = gatearr[row] / ssum;
        int orow = rowarr[row] & 0xFFFF;
        float* yr = y + (size_t)orow * 512 + w * 64 + lr;
        #pragma unroll
        for (int nf = 0; nf < 4; nf++) {
          atomicAdd(yr + nf * 16, acc2[mf][nf][q] * sc);
        }
      }
    }
  }
}

// ---------------- launch ----------------
extern "C" void kernel_launch(void* const* d_in, const int* in_sizes, int n_in,
                              void* d_out, int out_size, void* d_ws, size_t ws_size,
                              hipStream_t stream) {
  (void)in_sizes; (void)n_in; (void)out_size; (void)ws_size;
  const float* x  = (const float*)d_in[0];
  const float* wg = (const float*)d_in[1];
  const float* w1 = (const float*)d_in[2];
  const float* b1 = (const float*)d_in[3];
  const float* w2 = (const float*)d_in[4];
  const float* b2 = (const float*)d_in[5];
  float* y = (float*)d_out;

  char* ws = (char*)d_ws;
  size_t off = 0;
  auto alloc = [&](size_t bytes) -> char* {
    char* p = ws + off;
    off += (bytes + 255) & ~(size_t)255;
    return p;
  };
  f16*   w1fr       = (f16*)  alloc((size_t)16 * 512 * 1024 * 2);
  f16*   w2fr       = (f16*)  alloc((size_t)16 * 1024 * 512 * 2);
  int*   tk_idx     = (int*)  alloc((size_t)16384 * 4 * 4);
  float* tk_gate    = (float*)alloc((size_t)16384 * 4 * 4);
  int*   rows_pk    = (int*)  alloc((size_t)16 * 16384 * 4);
  float* gates_l    = (float*)alloc((size_t)16 * 16384 * 4);
  int*   partial    = (int*)  alloc(16 * 64 * 4);
  int*   chunk_base = (int*)  alloc(16 * 64 * 4);
  int*   count      = (int*)  alloc(256);
  // total ~34.6 MB (known-safe)

  k_cvt_w1<<<dim3(4096), dim3(256), 0, stream>>>(w1, w1fr);
  k_cvt_w2<<<dim3(4096), dim3(256), 0, stream>>>(w2, w2fr);
  k_gate<<<dim3(4096), dim3(256), 0, stream>>>(x, wg, tk_idx, tk_gate);
  k_route_count<<<dim3(1024), dim3(256), 0, stream>>>(tk_idx, partial);
  k_route_scan<<<dim3(1), dim3(64), 0, stream>>>(partial, chunk_base, count);
  k_route_scatter<<<dim3(1024), dim3(256), 0, stream>>>(tk_idx, tk_gate, chunk_base,
                                                        rows_pk, gates_l);
  k_zero<<<dim3(8192), dim3(256), 0, stream>>>((float4*)y);
  k_expert<<<dim3(4096), dim3(512), 0, stream>>>(x, w1fr, w2fr, b1, b2,
                                                 count, rows_pk, gates_l, y);
}